// Round 7
// baseline (175.096 us; speedup 1.0000x reference)
//
#include <hip/hip_runtime.h>
#include <hip/hip_bf16.h>
#include <cmath>

#define N_NODES 2000
#define BS 8

typedef __attribute__((ext_vector_type(8))) short short8v;
typedef __attribute__((ext_vector_type(4))) float float4v;

__device__ __forceinline__ float elu_f(float v) { return v > 0.f ? v : expm1f(v); }

__device__ __forceinline__ short f32_bf16(float f) {
    __hip_bfloat16 h = __float2bfloat16(f);
    unsigned short u;
    __builtin_memcpy(&u, &h, 2);
    return (short)u;
}

// w = mask_bit(lane) ? w : 0 — wave-uniform 64-bit mask as lane predicate (R5-proven)
__device__ __forceinline__ float sel_mask(float w, unsigned long long m) {
    float r;
    asm("v_cndmask_b32 %0, 0, %1, %2" : "=v"(r) : "v"(w), "s"(m));
    return r;
}

// ---------------- pack: adj bitmasks (u64 + u32, transposed) + s1/d1 + hT pad zero ----
__global__ __launch_bounds__(256) void pack_kernel(
    const float* __restrict__ adj, const float* __restrict__ x,
    const float* __restrict__ W1, const float* __restrict__ a1,
    unsigned long long* __restrict__ maskT, unsigned* __restrict__ maskT32,
    float* __restrict__ s1, float* __restrict__ d1,
    short* __restrict__ hT) {
    int bx = blockIdx.x;
    int tid = threadIdx.x;
    if (bx < N_NODES) {
        int row = bx;
        int lane = tid & 63, wv = tid >> 6;
        for (int wq = wv; wq < 32; wq += 4) {
            int j = wq * 64 + lane;
            bool on = (j < N_NODES) && (adj[(size_t)row * N_NODES + j] > 0.f);
            unsigned long long bal = __ballot(on);
            if (lane == 0) {
                maskT[(size_t)wq * 2048 + row] = bal;
                maskT32[(size_t)(2 * wq) * 2048 + row] = (unsigned)bal;
                maskT32[(size_t)(2 * wq + 1) * 2048 + row] = (unsigned)(bal >> 32);
            }
        }
        return;
    }
    if (bx < N_NODES + 32) {
        int bh = bx - N_NODES;  // 0..31
        int b = bh >> 2, h = bh & 3;
        float ws = 0.f, wd = 0.f;
        #pragma unroll
        for (int f = 0; f < 8; ++f) {
            float wv = W1[h * 8 + f];
            ws = fmaf(wv, a1[h * 16 + f], ws);
            wd = fmaf(wv, a1[h * 16 + 8 + f], wd);
        }
        for (int n = tid; n < N_NODES; n += 256) {
            float xv = x[b * N_NODES + n];
            s1[(size_t)bh * N_NODES + n] = xv * ws;
            d1[(size_t)bh * N_NODES + n] = xv * wd;
        }
        return;
    }
    // zero hT padding columns [2000,2048) for all 24 bh x 16 f
    for (int i = tid; i < 24 * 16 * 48; i += 256) {
        int bh = i / 768, rem = i % 768, f = rem / 48, n = N_NODES + rem % 48;
        hT[((size_t)bh * 16 + f) * 2048 + n] = 0;
    }
}

// ---------------- att1: scalar f32, 8 rows/wave, in-kernel md/PQ, slim LDS ----------
__global__ __launch_bounds__(256) void att1_kernel(
    const unsigned long long* __restrict__ maskT,
    const float* __restrict__ x,
    const float* __restrict__ s1, const float* __restrict__ d1,
    const float* __restrict__ W1,
    float* __restrict__ o1) {
    __shared__ float2 sPQ[2048];
    __shared__ float red[256];
    int tid = threadIdx.x;
    int head = blockIdx.y, b = blockIdx.z, bh = b * 4 + head;
    const float* dp = d1 + (size_t)bh * N_NODES;

    float mx = -1e30f;
    for (int n = tid; n < N_NODES; n += 256) mx = fmaxf(mx, dp[n]);
    red[tid] = mx;
    __syncthreads();
    for (int s = 128; s > 0; s >>= 1) {
        if (tid < s) red[tid] = fmaxf(red[tid], red[tid + s]);
        __syncthreads();
    }
    float md = red[0];
    for (int n = tid; n < 2048; n += 256) {
        if (n < N_NODES) {
            float d = dp[n] - md;
            sPQ[n] = make_float2(__expf(d), __expf(0.2f * d));
        } else {
            sPQ[n] = make_float2(0.f, 0.f);
        }
    }
    __syncthreads();

    int lane = tid & 63;
    int wave = __builtin_amdgcn_readfirstlane(tid >> 6);
    int t = blockIdx.x * 4 + wave;
    if (t >= 250) return;
    int row0 = t * 8;

    float Ar[8], Br[8], num[8], den[8];
    #pragma unroll
    for (int r = 0; r < 8; ++r) {
        float sv = s1[(size_t)bh * N_NODES + row0 + r];
        float u = sv + md, ub = fmaxf(u, 0.2f * u);
        Ar[r] = __expf(u - ub);
        Br[r] = __expf(0.2f * u - ub);
        num[r] = 0.f; den[r] = 0.f;
    }

    for (int j0 = 0; j0 < 2048; j0 += 64) {
        int j = j0 + lane;
        float2 pq = sPQ[j];
        float xv = (j < N_NODES) ? x[(size_t)b * N_NODES + j] : 0.f;
        const unsigned long long* mrow = maskT + ((size_t)(j0 >> 6) << 11) + row0;
        #pragma unroll
        for (int r = 0; r < 8; ++r) {
            float w = fmaxf(Ar[r] * pq.x, Br[r] * pq.y);
            w = sel_mask(w, mrow[r]);
            num[r] = fmaf(w, xv, num[r]);
            den[r] += w;
        }
    }
    #pragma unroll
    for (int off = 32; off >= 1; off >>= 1) {
        #pragma unroll
        for (int r = 0; r < 8; ++r) {
            num[r] += __shfl_xor(num[r], off, 64);
            den[r] += __shfl_xor(den[r], off, 64);
        }
    }
    if (lane < 8) {
        float wf = W1[head * 8 + lane];
        #pragma unroll
        for (int r = 0; r < 8; ++r) {
            float ratio = den[r] > 0.f ? num[r] / den[r] : 0.f;
            float v = ratio * wf;
            o1[((size_t)(b * N_NODES + row0 + r)) * 32 + head * 8 + lane] =
                v > 0.f ? v : expm1f(v);
        }
    }
}

// ---------------- prep2: h2 = o1@W2 (bf16 hT [bh][f][2048]); s2/d2 (R5-proven) -------
__global__ __launch_bounds__(256) void prep2_kernel(
    const float* __restrict__ o1, const float* __restrict__ W2,
    const float* __restrict__ a2,
    short* __restrict__ hT, float* __restrict__ s2, float* __restrict__ d2) {
    __shared__ float sW[1536];
    int tid = threadIdx.x;
    for (int i = tid; i < 1536; i += 256) sW[i] = W2[i];
    __syncthreads();
    int idx = blockIdx.x * 256 + tid;
    if (idx >= BS * 3 * N_NODES) return;
    int b = idx / 6000, r = idx % 6000, h = r / N_NODES, n = r % N_NODES;
    int bh = b * 3 + h;
    float in[32];
    const float4* ip = (const float4*)(o1 + ((size_t)b * N_NODES + n) * 32);
    #pragma unroll
    for (int q = 0; q < 8; ++q) {
        float4 v = ip[q];
        in[4 * q] = v.x; in[4 * q + 1] = v.y; in[4 * q + 2] = v.z; in[4 * q + 3] = v.w;
    }
    float hv[16];
    #pragma unroll
    for (int f = 0; f < 16; ++f) hv[f] = 0.f;
    #pragma unroll
    for (int k = 0; k < 32; ++k) {
        float ik = in[k];
        #pragma unroll
        for (int f = 0; f < 16; ++f) hv[f] = fmaf(ik, sW[h * 512 + k * 16 + f], hv[f]);
    }
    float sr = 0.f, ds = 0.f;
    #pragma unroll
    for (int f = 0; f < 16; ++f) {
        hT[((size_t)bh * 16 + f) * 2048 + n] = f32_bf16(hv[f]);
        sr = fmaf(hv[f], a2[h * 32 + f], sr);
        ds = fmaf(hv[f], a2[h * 32 + 16 + f], ds);
    }
    s2[(size_t)bh * N_NODES + n] = sr;
    d2[(size_t)bh * N_NODES + n] = ds;
}

// ---------------- att2: bf16 MFMA 16x16x32 (R5-proven core), in-kernel md/PQ --------
__global__ __launch_bounds__(256) void att2_kernel(
    const unsigned* __restrict__ maskT32,
    const short* __restrict__ hT,
    const float* __restrict__ s2, const float* __restrict__ d2,
    float* __restrict__ o2) {
    __shared__ float2 sPQ[2048];
    __shared__ float red[256];
    int tid = threadIdx.x;
    int head = blockIdx.y, b = blockIdx.z, bh = b * 3 + head;
    const float* dp = d2 + (size_t)bh * N_NODES;

    float mx = -1e30f;
    for (int n = tid; n < N_NODES; n += 256) mx = fmaxf(mx, dp[n]);
    red[tid] = mx;
    __syncthreads();
    for (int s = 128; s > 0; s >>= 1) {
        if (tid < s) red[tid] = fmaxf(red[tid], red[tid + s]);
        __syncthreads();
    }
    float md = red[0];
    for (int n = tid; n < 2048; n += 256) {
        if (n < N_NODES) {
            float d = dp[n] - md;
            sPQ[n] = make_float2(__expf(d), __expf(0.2f * d));
        } else {
            sPQ[n] = make_float2(0.f, 0.f);
        }
    }
    __syncthreads();

    int lane = tid & 63;
    int wave = __builtin_amdgcn_readfirstlane(tid >> 6);
    int t = blockIdx.x * 4 + wave;
    if (t >= 125) return;
    int rs = lane & 15;      // A row in tile == C col (feature)
    int g = lane >> 4;       // k-group
    int row = t * 16 + rs;

    float sv = s2[(size_t)bh * N_NODES + row];
    float u = sv + md, ub = fmaxf(u, 0.2f * u);
    float Ar = __expf(u - ub), Br = __expf(0.2f * u - ub);
    const short* hb = hT + ((size_t)bh * 16 + rs) * 2048;

    float4v acc = {0.f, 0.f, 0.f, 0.f};
    float den = 0.f;

    for (int jc = 0; jc < 64; ++jc) {
        int jb = jc * 32 + g * 8;
        float w[8];
        #pragma unroll
        for (int e2 = 0; e2 < 4; ++e2) {
            float4 pq2 = *(const float4*)(&sPQ[jb + e2 * 2]);  // P0,Q0,P1,Q1
            w[e2 * 2 + 0] = fmaxf(Ar * pq2.x, Br * pq2.y);
            w[e2 * 2 + 1] = fmaxf(Ar * pq2.z, Br * pq2.w);
        }
        unsigned mby = maskT32[(size_t)jc * 2048 + row] >> (g * 8);
        short8v av;
        #pragma unroll
        for (int e = 0; e < 8; ++e) {
            float we = (mby & (1u << e)) ? w[e] : 0.f;
            den += we;
            av[e] = f32_bf16(we);
        }
        short8v bv = *(const short8v*)(hb + jb);
        acc = __builtin_amdgcn_mfma_f32_16x16x32_bf16(av, bv, acc, 0, 0, 0);
    }

    den += __shfl_xor(den, 16, 64);
    den += __shfl_xor(den, 32, 64);
    float inv = den > 0.f ? 1.0f / den : 0.f;   // valid for row rs

    #pragma unroll
    for (int reg = 0; reg < 4; ++reg) {
        int crow = g * 4 + reg;
        float invr = __shfl(inv, crow, 64);
        float v = acc[reg] * invr;
        v = v > 0.f ? v : expm1f(v);
        o2[((size_t)(b * N_NODES + t * 16 + crow)) * 48 + head * 16 + rs] = v;
    }
}

// ---------------- fc1 split-K with inline concat/projection staging ----------------
__global__ __launch_bounds__(256) void fc1_splitk_kernel(
    const float* __restrict__ x,
    const float* __restrict__ o1, const float* __restrict__ o2,
    const float* __restrict__ pw1, const float* __restrict__ pb1,
    const float* __restrict__ pw2, const float* __restrict__ pb2,
    const float* __restrict__ W, float* __restrict__ partial) {
    const int K = 6000, O = 600, KS = 71;
    __shared__ float sz[BS][KS];
    int tid = threadIdx.x;
    int kt = blockIdx.y;
    int k0 = kt * KS;
    int len = (k0 + KS <= K) ? KS : (K - k0);
    float pb1v = pb1[0], pb2v = pb2[0];
    for (int i = tid; i < BS * len; i += 256) {
        int bb = i / len, k = k0 + i % len;
        float v;
        if (k < 2000) {
            v = x[bb * 2000 + k];
        } else if (k < 4000) {
            const float* op = o1 + ((size_t)bb * 2000 + (k - 2000)) * 32;
            float s = pb1v;
            #pragma unroll
            for (int q = 0; q < 32; ++q) s = fmaf(op[q], pw1[q], s);
            v = s;
        } else {
            const float* op = o2 + ((size_t)bb * 2000 + (k - 4000)) * 48;
            float s = pb2v;
            #pragma unroll
            for (int q = 0; q < 48; ++q) s = fmaf(op[q], pw2[q], s);
            v = s;
        }
        sz[bb][i % len] = v;
    }
    __syncthreads();
    int o = blockIdx.x * 256 + tid;
    float acc[BS] = {0.f, 0.f, 0.f, 0.f, 0.f, 0.f, 0.f, 0.f};
    if (o < O) {
        for (int k = 0; k < len; ++k) {
            float w = W[(size_t)(k0 + k) * O + o];
            #pragma unroll
            for (int b = 0; b < BS; ++b) acc[b] = fmaf(sz[b][k], w, acc[b]);
        }
        #pragma unroll
        for (int b = 0; b < BS; ++b)
            partial[((size_t)kt * BS + b) * O + o] = acc[b];
    }
}

// ---------------- fc_final: fc1-reduce + fc2 + fc3 + fc4 + fc5 ----------------
__global__ __launch_bounds__(256) void fc_final_kernel(
    const float* __restrict__ p1, const float* __restrict__ b1,
    const float* __restrict__ w2, const float* __restrict__ b2,
    const float* __restrict__ w3, const float* __restrict__ b3,
    const float* __restrict__ w4, const float* __restrict__ b4,
    const float* __restrict__ w5, const float* __restrict__ b5,
    float* __restrict__ outp) {
    int b = blockIdx.x, tid = threadIdx.x;
    __shared__ float t1[600], t2[256], red[256], z1[64], z4[32];
    for (int o = tid; o < 600; o += 256) {
        float a = b1[o];
        #pragma unroll 4
        for (int kt = 0; kt < 85; ++kt) a += p1[((size_t)kt * BS + b) * 600 + o];
        t1[o] = elu_f(a);
    }
    __syncthreads();
    {
        int o = tid;
        float a = b2[o];
        #pragma unroll 8
        for (int k = 0; k < 600; ++k) a = fmaf(t1[k], w2[(size_t)k * 256 + o], a);
        t2[o] = elu_f(a);
    }
    __syncthreads();
    {
        int o = tid & 63, ks = tid >> 6;
        float a = 0.f;
        for (int k = ks; k < 256; k += 4) a = fmaf(t2[k], w3[k * 64 + o], a);
        red[tid] = a;
        __syncthreads();
        if (ks == 0) {
            float v = red[o] + red[64 + o] + red[128 + o] + red[192 + o] + b3[o];
            v = elu_f(v);
            z1[o] = v;
            outp[b * 64 + o] = v;
        }
    }
    __syncthreads();
    if (tid < 32) {
        float v = b4[tid];
        #pragma unroll
        for (int k = 0; k < 64; ++k) v = fmaf(z1[k], w4[k * 32 + tid], v);
        z4[tid] = elu_f(v);
    }
    __syncthreads();
    if (tid < 2) {
        float v = b5[tid];
        #pragma unroll
        for (int k = 0; k < 32; ++k) v = fmaf(z4[k], w5[k * 2 + tid], v);
        outp[BS * 64 + b * 2 + tid] = v;
    }
}

extern "C" void kernel_launch(void* const* d_in, const int* in_sizes, int n_in,
                              void* d_out, int out_size, void* d_ws, size_t ws_size,
                              hipStream_t stream) {
    const float* x    = (const float*)d_in[0];
    const float* adj  = (const float*)d_in[1];
    const float* W1   = (const float*)d_in[2];
    const float* a1   = (const float*)d_in[3];
    const float* W2   = (const float*)d_in[4];
    const float* a2   = (const float*)d_in[5];
    const float* pw1  = (const float*)d_in[6];
    const float* pb1  = (const float*)d_in[7];
    const float* pw2  = (const float*)d_in[8];
    const float* pb2  = (const float*)d_in[9];
    const float* fc1w = (const float*)d_in[10];
    const float* fc1b = (const float*)d_in[11];
    const float* fc2w = (const float*)d_in[12];
    const float* fc2b = (const float*)d_in[13];
    const float* fc3w = (const float*)d_in[14];
    const float* fc3b = (const float*)d_in[15];
    const float* fc4w = (const float*)d_in[16];
    const float* fc4b = (const float*)d_in[17];
    const float* fc5w = (const float*)d_in[18];
    const float* fc5b = (const float*)d_in[19];
    float* outp = (float*)d_out;

    float* ws = (float*)d_ws;
    size_t off = 0;
    auto alloc = [&](size_t n) {
        float* p = ws + off;
        off += (n + 63) & ~(size_t)63;
        return p;
    };
    float* s1 = alloc((size_t)32 * N_NODES);
    float* d1 = alloc((size_t)32 * N_NODES);
    float* o1 = alloc((size_t)BS * N_NODES * 32);
    float* s2 = alloc((size_t)24 * N_NODES);
    float* d2 = alloc((size_t)24 * N_NODES);
    short* hT = (short*)alloc((size_t)24 * 16 * 2048 / 2);
    float* o2 = alloc((size_t)BS * N_NODES * 48);
    const int KT1 = 85;
    float* p1 = alloc((size_t)KT1 * BS * 600);
    unsigned long long* maskT = (unsigned long long*)alloc((size_t)32 * 2048 * 2);
    unsigned* maskT32 = (unsigned*)alloc((size_t)64 * 2048);

    pack_kernel<<<N_NODES + 32 + 1, 256, 0, stream>>>(
        adj, x, W1, a1, maskT, maskT32, s1, d1, hT);
    att1_kernel<<<dim3(63, 4, BS), 256, 0, stream>>>(maskT, x, s1, d1, W1, o1);
    prep2_kernel<<<(BS * 3 * N_NODES + 255) / 256, 256, 0, stream>>>(o1, W2, a2, hT, s2, d2);
    att2_kernel<<<dim3(32, 3, BS), 256, 0, stream>>>(maskT32, hT, s2, d2, o2);
    fc1_splitk_kernel<<<dim3(3, KT1), 256, 0, stream>>>(
        x, o1, o2, pw1, pb1, pw2, pb2, fc1w, p1);
    fc_final_kernel<<<BS, 256, 0, stream>>>(
        p1, fc1b, fc2w, fc2b, fc3w, fc3b, fc4w, fc4b, fc5w, fc5b, outp);
}

// Round 8
// 130.090 us; speedup vs baseline: 1.3460x; 1.3460x over previous
//
#include <hip/hip_runtime.h>
#include <hip/hip_bf16.h>
#include <cmath>

#define N_NODES 2000
#define BS 8

typedef __attribute__((ext_vector_type(8))) short short8v;
typedef __attribute__((ext_vector_type(4))) float float4v;

__device__ __forceinline__ float elu_f(float v) { return v > 0.f ? v : expm1f(v); }

__device__ __forceinline__ short f32_bf16(float f) {
    __hip_bfloat16 h = __float2bfloat16(f);
    unsigned short u;
    __builtin_memcpy(&u, &h, 2);
    return (short)u;
}

// w = mask_bit(lane) ? w : 0 — wave-uniform 64-bit mask as lane predicate (R5-proven)
__device__ __forceinline__ float sel_mask(float w, unsigned long long m) {
    float r;
    asm("v_cndmask_b32 %0, 0, %1, %2" : "=v"(r) : "v"(w), "s"(m));
    return r;
}

// ---------------- pack: adj bitmasks (u64 + u32, transposed) + s1/d1 + hT pad zero ----
__global__ __launch_bounds__(256) void pack_kernel(
    const float* __restrict__ adj, const float* __restrict__ x,
    const float* __restrict__ W1, const float* __restrict__ a1,
    unsigned long long* __restrict__ maskT, unsigned* __restrict__ maskT32,
    float* __restrict__ s1, float* __restrict__ d1,
    short* __restrict__ hT) {
    int bx = blockIdx.x;
    int tid = threadIdx.x;
    if (bx < N_NODES) {
        int row = bx;
        int lane = tid & 63, wv = tid >> 6;
        for (int wq = wv; wq < 32; wq += 4) {
            int j = wq * 64 + lane;
            bool on = (j < N_NODES) && (adj[(size_t)row * N_NODES + j] > 0.f);
            unsigned long long bal = __ballot(on);
            if (lane == 0) {
                maskT[(size_t)wq * 2048 + row] = bal;
                maskT32[(size_t)(2 * wq) * 2048 + row] = (unsigned)bal;
                maskT32[(size_t)(2 * wq + 1) * 2048 + row] = (unsigned)(bal >> 32);
            }
        }
        return;
    }
    if (bx < N_NODES + 32) {
        int bh = bx - N_NODES;  // 0..31
        int b = bh >> 2, h = bh & 3;
        float ws = 0.f, wd = 0.f;
        #pragma unroll
        for (int f = 0; f < 8; ++f) {
            float wv = W1[h * 8 + f];
            ws = fmaf(wv, a1[h * 16 + f], ws);
            wd = fmaf(wv, a1[h * 16 + 8 + f], wd);
        }
        for (int n = tid; n < N_NODES; n += 256) {
            float xv = x[b * N_NODES + n];
            s1[(size_t)bh * N_NODES + n] = xv * ws;
            d1[(size_t)bh * N_NODES + n] = xv * wd;
        }
        return;
    }
    // zero hT padding columns [2000,2048) for all 24 bh x 16 f
    for (int i = tid; i < 24 * 16 * 48; i += 256) {
        int bh = i / 768, rem = i % 768, f = rem / 48, n = N_NODES + rem % 48;
        hT[((size_t)bh * 16 + f) * 2048 + n] = 0;
    }
}

// ---------------- att1: scalar f32, 8 rows/wave, in-kernel md/PQ, slim LDS ----------
__global__ __launch_bounds__(256) void att1_kernel(
    const unsigned long long* __restrict__ maskT,
    const float* __restrict__ x,
    const float* __restrict__ s1, const float* __restrict__ d1,
    const float* __restrict__ W1,
    float* __restrict__ o1) {
    __shared__ float2 sPQ[2048];
    __shared__ float red[256];
    int tid = threadIdx.x;
    int head = blockIdx.y, b = blockIdx.z, bh = b * 4 + head;
    const float* dp = d1 + (size_t)bh * N_NODES;

    float mx = -1e30f;
    for (int n = tid; n < N_NODES; n += 256) mx = fmaxf(mx, dp[n]);
    red[tid] = mx;
    __syncthreads();
    for (int s = 128; s > 0; s >>= 1) {
        if (tid < s) red[tid] = fmaxf(red[tid], red[tid + s]);
        __syncthreads();
    }
    float md = red[0];
    for (int n = tid; n < 2048; n += 256) {
        if (n < N_NODES) {
            float d = dp[n] - md;
            sPQ[n] = make_float2(__expf(d), __expf(0.2f * d));
        } else {
            sPQ[n] = make_float2(0.f, 0.f);
        }
    }
    __syncthreads();

    int lane = tid & 63;
    int wave = __builtin_amdgcn_readfirstlane(tid >> 6);
    int t = blockIdx.x * 4 + wave;
    if (t >= 250) return;
    int row0 = t * 8;

    float Ar[8], Br[8], num[8], den[8];
    #pragma unroll
    for (int r = 0; r < 8; ++r) {
        float sv = s1[(size_t)bh * N_NODES + row0 + r];
        float u = sv + md, ub = fmaxf(u, 0.2f * u);
        Ar[r] = __expf(u - ub);
        Br[r] = __expf(0.2f * u - ub);
        num[r] = 0.f; den[r] = 0.f;
    }

    for (int j0 = 0; j0 < 2048; j0 += 64) {
        int j = j0 + lane;
        float2 pq = sPQ[j];
        float xv = (j < N_NODES) ? x[(size_t)b * N_NODES + j] : 0.f;
        const unsigned long long* mrow = maskT + ((size_t)(j0 >> 6) << 11) + row0;
        #pragma unroll
        for (int r = 0; r < 8; ++r) {
            float w = fmaxf(Ar[r] * pq.x, Br[r] * pq.y);
            w = sel_mask(w, mrow[r]);
            num[r] = fmaf(w, xv, num[r]);
            den[r] += w;
        }
    }
    #pragma unroll
    for (int off = 32; off >= 1; off >>= 1) {
        #pragma unroll
        for (int r = 0; r < 8; ++r) {
            num[r] += __shfl_xor(num[r], off, 64);
            den[r] += __shfl_xor(den[r], off, 64);
        }
    }
    if (lane < 8) {
        float wf = W1[head * 8 + lane];
        #pragma unroll
        for (int r = 0; r < 8; ++r) {
            float ratio = den[r] > 0.f ? num[r] / den[r] : 0.f;
            float v = ratio * wf;
            o1[((size_t)(b * N_NODES + row0 + r)) * 32 + head * 8 + lane] =
                v > 0.f ? v : expm1f(v);
        }
    }
}

// ---------------- prep2: h2 = o1@W2 (bf16 hT [bh][f][2048]); s2/d2 ----------------
__global__ __launch_bounds__(256) void prep2_kernel(
    const float* __restrict__ o1, const float* __restrict__ W2,
    const float* __restrict__ a2,
    short* __restrict__ hT, float* __restrict__ s2, float* __restrict__ d2) {
    __shared__ float sW[1536];
    int tid = threadIdx.x;
    for (int i = tid; i < 1536; i += 256) sW[i] = W2[i];
    __syncthreads();
    int idx = blockIdx.x * 256 + tid;
    if (idx >= BS * 3 * N_NODES) return;
    int b = idx / 6000, r = idx % 6000, h = r / N_NODES, n = r % N_NODES;
    int bh = b * 3 + h;
    float in[32];
    const float4* ip = (const float4*)(o1 + ((size_t)b * N_NODES + n) * 32);
    #pragma unroll
    for (int q = 0; q < 8; ++q) {
        float4 v = ip[q];
        in[4 * q] = v.x; in[4 * q + 1] = v.y; in[4 * q + 2] = v.z; in[4 * q + 3] = v.w;
    }
    float hv[16];
    #pragma unroll
    for (int f = 0; f < 16; ++f) hv[f] = 0.f;
    #pragma unroll
    for (int k = 0; k < 32; ++k) {
        float ik = in[k];
        #pragma unroll
        for (int f = 0; f < 16; ++f) hv[f] = fmaf(ik, sW[h * 512 + k * 16 + f], hv[f]);
    }
    float sr = 0.f, ds = 0.f;
    #pragma unroll
    for (int f = 0; f < 16; ++f) {
        hT[((size_t)bh * 16 + f) * 2048 + n] = f32_bf16(hv[f]);
        sr = fmaf(hv[f], a2[h * 32 + f], sr);
        ds = fmaf(hv[f], a2[h * 32 + 16 + f], ds);
    }
    s2[(size_t)bh * N_NODES + n] = sr;
    d2[(size_t)bh * N_NODES + n] = ds;
}

// ---------------- att2: bf16 MFMA 16x16x32, in-kernel md/PQ ----------------
__global__ __launch_bounds__(256) void att2_kernel(
    const unsigned* __restrict__ maskT32,
    const short* __restrict__ hT,
    const float* __restrict__ s2, const float* __restrict__ d2,
    float* __restrict__ o2) {
    __shared__ float2 sPQ[2048];
    __shared__ float red[256];
    int tid = threadIdx.x;
    int head = blockIdx.y, b = blockIdx.z, bh = b * 3 + head;
    const float* dp = d2 + (size_t)bh * N_NODES;

    float mx = -1e30f;
    for (int n = tid; n < N_NODES; n += 256) mx = fmaxf(mx, dp[n]);
    red[tid] = mx;
    __syncthreads();
    for (int s = 128; s > 0; s >>= 1) {
        if (tid < s) red[tid] = fmaxf(red[tid], red[tid + s]);
        __syncthreads();
    }
    float md = red[0];
    for (int n = tid; n < 2048; n += 256) {
        if (n < N_NODES) {
            float d = dp[n] - md;
            sPQ[n] = make_float2(__expf(d), __expf(0.2f * d));
        } else {
            sPQ[n] = make_float2(0.f, 0.f);
        }
    }
    __syncthreads();

    int lane = tid & 63;
    int wave = __builtin_amdgcn_readfirstlane(tid >> 6);
    int t = blockIdx.x * 4 + wave;
    if (t >= 125) return;
    int rs = lane & 15;      // A row in tile == C col (feature)
    int g = lane >> 4;       // k-group
    int row = t * 16 + rs;

    float sv = s2[(size_t)bh * N_NODES + row];
    float u = sv + md, ub = fmaxf(u, 0.2f * u);
    float Ar = __expf(u - ub), Br = __expf(0.2f * u - ub);
    const short* hb = hT + ((size_t)bh * 16 + rs) * 2048;

    float4v acc = {0.f, 0.f, 0.f, 0.f};
    float den = 0.f;

    for (int jc = 0; jc < 64; ++jc) {
        int jb = jc * 32 + g * 8;
        float w[8];
        #pragma unroll
        for (int e2 = 0; e2 < 4; ++e2) {
            float4 pq2 = *(const float4*)(&sPQ[jb + e2 * 2]);  // P0,Q0,P1,Q1
            w[e2 * 2 + 0] = fmaxf(Ar * pq2.x, Br * pq2.y);
            w[e2 * 2 + 1] = fmaxf(Ar * pq2.z, Br * pq2.w);
        }
        unsigned mby = maskT32[(size_t)jc * 2048 + row] >> (g * 8);
        short8v av;
        #pragma unroll
        for (int e = 0; e < 8; ++e) {
            float we = (mby & (1u << e)) ? w[e] : 0.f;
            den += we;
            av[e] = f32_bf16(we);
        }
        short8v bv = *(const short8v*)(hb + jb);
        acc = __builtin_amdgcn_mfma_f32_16x16x32_bf16(av, bv, acc, 0, 0, 0);
    }

    den += __shfl_xor(den, 16, 64);
    den += __shfl_xor(den, 32, 64);
    float inv = den > 0.f ? 1.0f / den : 0.f;   // valid for row rs

    #pragma unroll
    for (int reg = 0; reg < 4; ++reg) {
        int crow = g * 4 + reg;
        float invr = __shfl(inv, crow, 64);
        float v = acc[reg] * invr;
        v = v > 0.f ? v : expm1f(v);
        o2[((size_t)(b * N_NODES + t * 16 + crow)) * 48 + head * 16 + rs] = v;
    }
}

// ---------------- fc1 split-K with inline concat/projection staging ----------------
__global__ __launch_bounds__(256) void fc1_splitk_kernel(
    const float* __restrict__ x,
    const float* __restrict__ o1, const float* __restrict__ o2,
    const float* __restrict__ pw1, const float* __restrict__ pb1,
    const float* __restrict__ pw2, const float* __restrict__ pb2,
    const float* __restrict__ W, float* __restrict__ partial) {
    const int K = 6000, O = 600, KS = 71;
    __shared__ float sz[BS][KS];
    int tid = threadIdx.x;
    int kt = blockIdx.y;
    int k0 = kt * KS;
    int len = (k0 + KS <= K) ? KS : (K - k0);
    float pb1v = pb1[0], pb2v = pb2[0];
    for (int i = tid; i < BS * len; i += 256) {
        int bb = i / len, k = k0 + i % len;
        float v;
        if (k < 2000) {
            v = x[bb * 2000 + k];
        } else if (k < 4000) {
            const float* op = o1 + ((size_t)bb * 2000 + (k - 2000)) * 32;
            float s = pb1v;
            #pragma unroll
            for (int q = 0; q < 32; ++q) s = fmaf(op[q], pw1[q], s);
            v = s;
        } else {
            const float* op = o2 + ((size_t)bb * 2000 + (k - 4000)) * 48;
            float s = pb2v;
            #pragma unroll
            for (int q = 0; q < 48; ++q) s = fmaf(op[q], pw2[q], s);
            v = s;
        }
        sz[bb][i % len] = v;
    }
    __syncthreads();
    int o = blockIdx.x * 256 + tid;
    float acc[BS] = {0.f, 0.f, 0.f, 0.f, 0.f, 0.f, 0.f, 0.f};
    if (o < O) {
        for (int k = 0; k < len; ++k) {
            float w = W[(size_t)(k0 + k) * O + o];
            #pragma unroll
            for (int b = 0; b < BS; ++b) acc[b] = fmaf(sz[b][k], w, acc[b]);
        }
        #pragma unroll
        for (int b = 0; b < BS; ++b)
            partial[((size_t)kt * BS + b) * O + o] = acc[b];
    }
}

// ---------------- fc_reduce1: t1 = elu(bias + sum_kt p1) — grid (3, BS) ----------------
__global__ __launch_bounds__(256) void fc_reduce1_kernel(
    const float* __restrict__ p1, const float* __restrict__ bias,
    float* __restrict__ t1) {
    int o = blockIdx.x * 256 + threadIdx.x;
    int b = blockIdx.y;
    if (o >= 600) return;
    float a = bias[o];
    #pragma unroll 5
    for (int kt = 0; kt < 85; ++kt) a += p1[((size_t)kt * BS + b) * 600 + o];
    t1[(size_t)b * 600 + o] = elu_f(a);
}

// ---------------- fc2 split-K: t1[8][600] x w2[600][256] -> p2 — grid (1, 16) --------
__global__ __launch_bounds__(256) void fc2_splitk_kernel(
    const float* __restrict__ in, const float* __restrict__ W,
    float* __restrict__ partial) {
    const int K = 600, O = 256, KS = 38;
    __shared__ float sz[BS][KS];
    int tid = threadIdx.x;
    int kt = blockIdx.y;
    int k0 = kt * KS;
    int k1 = k0 + KS < K ? k0 + KS : K;
    int len = k1 - k0;
    for (int i = tid; i < BS * len; i += 256)
        sz[i / len][i % len] = in[(size_t)(i / len) * K + k0 + i % len];
    __syncthreads();
    int o = tid;
    float acc[BS] = {0.f, 0.f, 0.f, 0.f, 0.f, 0.f, 0.f, 0.f};
    for (int k = 0; k < len; ++k) {
        float w = W[(size_t)(k0 + k) * O + o];
        #pragma unroll
        for (int b = 0; b < BS; ++b) acc[b] = fmaf(sz[b][k], w, acc[b]);
    }
    #pragma unroll
    for (int b = 0; b < BS; ++b)
        partial[((size_t)kt * BS + b) * O + o] = acc[b];
}

// ---------------- fc_tail: p2-reduce + fc3 + fc4 + fc5 — grid (BS) ----------------
__global__ __launch_bounds__(256) void fc_tail_kernel(
    const float* __restrict__ p2, const float* __restrict__ b2,
    const float* __restrict__ w3, const float* __restrict__ b3,
    const float* __restrict__ w4, const float* __restrict__ b4,
    const float* __restrict__ w5, const float* __restrict__ b5,
    float* __restrict__ outp) {
    int b = blockIdx.x, tid = threadIdx.x;
    __shared__ float t2[256], red[256], z1[64], z4[32];
    {
        float a = b2[tid];
        #pragma unroll
        for (int kt = 0; kt < 16; ++kt) a += p2[((size_t)kt * BS + b) * 256 + tid];
        t2[tid] = elu_f(a);
    }
    __syncthreads();
    {
        int o = tid & 63, ks = tid >> 6;
        float a = 0.f;
        for (int k = ks; k < 256; k += 4) a = fmaf(t2[k], w3[k * 64 + o], a);
        red[tid] = a;
        __syncthreads();
        if (ks == 0) {
            float v = red[o] + red[64 + o] + red[128 + o] + red[192 + o] + b3[o];
            v = elu_f(v);
            z1[o] = v;
            outp[b * 64 + o] = v;
        }
    }
    __syncthreads();
    if (tid < 32) {
        float v = b4[tid];
        #pragma unroll
        for (int k = 0; k < 64; ++k) v = fmaf(z1[k], w4[k * 32 + tid], v);
        z4[tid] = elu_f(v);
    }
    __syncthreads();
    if (tid < 2) {
        float v = b5[tid];
        #pragma unroll
        for (int k = 0; k < 32; ++k) v = fmaf(z4[k], w5[k * 2 + tid], v);
        outp[BS * 64 + b * 2 + tid] = v;
    }
}

extern "C" void kernel_launch(void* const* d_in, const int* in_sizes, int n_in,
                              void* d_out, int out_size, void* d_ws, size_t ws_size,
                              hipStream_t stream) {
    const float* x    = (const float*)d_in[0];
    const float* adj  = (const float*)d_in[1];
    const float* W1   = (const float*)d_in[2];
    const float* a1   = (const float*)d_in[3];
    const float* W2   = (const float*)d_in[4];
    const float* a2   = (const float*)d_in[5];
    const float* pw1  = (const float*)d_in[6];
    const float* pb1  = (const float*)d_in[7];
    const float* pw2  = (const float*)d_in[8];
    const float* pb2  = (const float*)d_in[9];
    const float* fc1w = (const float*)d_in[10];
    const float* fc1b = (const float*)d_in[11];
    const float* fc2w = (const float*)d_in[12];
    const float* fc2b = (const float*)d_in[13];
    const float* fc3w = (const float*)d_in[14];
    const float* fc3b = (const float*)d_in[15];
    const float* fc4w = (const float*)d_in[16];
    const float* fc4b = (const float*)d_in[17];
    const float* fc5w = (const float*)d_in[18];
    const float* fc5b = (const float*)d_in[19];
    float* outp = (float*)d_out;

    float* ws = (float*)d_ws;
    size_t off = 0;
    auto alloc = [&](size_t n) {
        float* p = ws + off;
        off += (n + 63) & ~(size_t)63;
        return p;
    };
    float* s1 = alloc((size_t)32 * N_NODES);
    float* d1 = alloc((size_t)32 * N_NODES);
    float* o1 = alloc((size_t)BS * N_NODES * 32);
    float* s2 = alloc((size_t)24 * N_NODES);
    float* d2 = alloc((size_t)24 * N_NODES);
    short* hT = (short*)alloc((size_t)24 * 16 * 2048 / 2);
    float* o2 = alloc((size_t)BS * N_NODES * 48);
    const int KT1 = 85;
    float* p1 = alloc((size_t)KT1 * BS * 600);
    float* t1 = alloc((size_t)BS * 600);
    float* p2 = alloc((size_t)16 * BS * 256);
    unsigned long long* maskT = (unsigned long long*)alloc((size_t)32 * 2048 * 2);
    unsigned* maskT32 = (unsigned*)alloc((size_t)64 * 2048);

    pack_kernel<<<N_NODES + 32 + 1, 256, 0, stream>>>(
        adj, x, W1, a1, maskT, maskT32, s1, d1, hT);
    att1_kernel<<<dim3(63, 4, BS), 256, 0, stream>>>(maskT, x, s1, d1, W1, o1);
    prep2_kernel<<<(BS * 3 * N_NODES + 255) / 256, 256, 0, stream>>>(o1, W2, a2, hT, s2, d2);
    att2_kernel<<<dim3(32, 3, BS), 256, 0, stream>>>(maskT32, hT, s2, d2, o2);
    fc1_splitk_kernel<<<dim3(3, KT1), 256, 0, stream>>>(
        x, o1, o2, pw1, pb1, pw2, pb2, fc1w, p1);
    fc_reduce1_kernel<<<dim3(3, BS), 256, 0, stream>>>(p1, fc1b, t1);
    fc2_splitk_kernel<<<dim3(1, 16), 256, 0, stream>>>(t1, fc2w, p2);
    fc_tail_kernel<<<BS, 256, 0, stream>>>(
        p2, fc2b, fc3w, fc3b, fc4w, fc4b, fc5w, fc5b, outp);
}